// Round 1
// baseline (1293.637 us; speedup 1.0000x reference)
//
#include <hip/hip_runtime.h>
#include <hip/hip_bf16.h>

// out[i] = sum_j S[i][j] * w[j]   (N x N fp32 matvec, N=16384)
// One 64-lane wave per row; float4 loads; shuffle reduction.

__global__ __launch_bounds__(256) void matvec_rowwave_kernel(
    const float* __restrict__ S,
    const float* __restrict__ w,
    float* __restrict__ out,
    int N)
{
    const int gtid  = blockIdx.x * blockDim.x + threadIdx.x;
    const int wave  = gtid >> 6;        // global wave index == row index
    const int lane  = threadIdx.x & 63;
    if (wave >= N) return;

    const float4* __restrict__ row = (const float4*)(S + (size_t)wave * (size_t)N);
    const float4* __restrict__ w4  = (const float4*)w;
    const int nv = N >> 2;              // float4 elements per row (4096)

    float acc = 0.0f;
    // 64 iterations/lane at N=16384: lane j reads row[j], row[j+64], ...
    for (int j = lane; j < nv; j += 64) {
        float4 s  = row[j];
        float4 ww = w4[j];
        acc += s.x * ww.x + s.y * ww.y + s.z * ww.z + s.w * ww.w;
    }

    // 64-lane butterfly/down reduction
    #pragma unroll
    for (int off = 32; off > 0; off >>= 1)
        acc += __shfl_down(acc, off, 64);

    if (lane == 0) out[wave] = acc;
}

extern "C" void kernel_launch(void* const* d_in, const int* in_sizes, int n_in,
                              void* d_out, int out_size, void* d_ws, size_t ws_size,
                              hipStream_t stream) {
    const float* S = (const float*)d_in[0];
    const float* w = (const float*)d_in[1];
    float* out     = (float*)d_out;
    const int N    = in_sizes[1];       // 16384

    // one wave per row -> N waves; 4 waves (256 threads) per block
    const int threads = 256;
    const int blocks  = (N * 64 + threads - 1) / threads;
    matvec_rowwave_kernel<<<blocks, threads, 0, stream>>>(S, w, out, N);
}